// Round 1
// baseline (215.279 us; speedup 1.0000x reference)
//
#include <hip/hip_runtime.h>
#include <math.h>

// R = I + a*K + b*K^2 with K=skew(v), K^2 = v v^T - th^2 I
// => R = (1 - b*th^2) I + b * v v^T + a * K   (exactly the reference formula,
//    including the small-angle branch a=1, b=0.5)
__device__ __forceinline__ void rodrigues(const float v0, const float v1, const float v2,
                                          float R[9]) {
    float th2 = v0 * v0 + v1 * v1 + v2 * v2;
    float th  = sqrtf(th2);
    float s, c;
    sincosf(th, &s, &c);
    bool  sm = th < 1e-6f;
    float a  = sm ? 1.0f : s / th;
    float b  = sm ? 0.5f : (1.0f - c) / th2;
    float cc = 1.0f - b * th2;   // == cos(th) for the large branch
    R[0] = cc + b * v0 * v0;  R[1] = b * v0 * v1 - a * v2;  R[2] = b * v0 * v2 + a * v1;
    R[3] = b * v0 * v1 + a * v2;  R[4] = cc + b * v1 * v1;  R[5] = b * v1 * v2 - a * v0;
    R[6] = b * v0 * v2 - a * v1;  R[7] = b * v1 * v2 + a * v0;  R[8] = cc + b * v2 * v2;
}

// 4 elements per thread: all global traffic is float4 (16 B/lane).
__global__ __launch_bounds__(256) void aff_kernel(
    const float4* __restrict__ trans,
    const float4* __restrict__ rotat,
    const float4* __restrict__ sdir,
    const float4* __restrict__ scal,
    float4* __restrict__ out,
    int nq)   // nq = B/4
{
    int t = blockIdx.x * blockDim.x + threadIdx.x;
    if (t >= nq) return;

    // Each group of 4 elements = 12 floats = 3 float4 per input.
    float4 tr4[3], ro4[3], sd4[3], sc4[3];
#pragma unroll
    for (int i = 0; i < 3; ++i) {
        tr4[i] = trans[3 * t + i];
        ro4[i] = rotat[3 * t + i];
        sd4[i] = sdir [3 * t + i];
        sc4[i] = scal [3 * t + i];
    }
    // Flatten to 12-float register arrays (fully unrolled -> stays in VGPRs).
    float tr[12], ro[12], sd[12], sc[12];
#pragma unroll
    for (int i = 0; i < 3; ++i) {
        tr[4*i+0]=tr4[i].x; tr[4*i+1]=tr4[i].y; tr[4*i+2]=tr4[i].z; tr[4*i+3]=tr4[i].w;
        ro[4*i+0]=ro4[i].x; ro[4*i+1]=ro4[i].y; ro[4*i+2]=ro4[i].z; ro[4*i+3]=ro4[i].w;
        sd[4*i+0]=sd4[i].x; sd[4*i+1]=sd4[i].y; sd[4*i+2]=sd4[i].z; sd[4*i+3]=sd4[i].w;
        sc[4*i+0]=sc4[i].x; sc[4*i+1]=sc4[i].y; sc[4*i+2]=sc4[i].z; sc[4*i+3]=sc4[i].w;
    }

#pragma unroll
    for (int e = 0; e < 4; ++e) {
        float R[9], U[9];
        rodrigues(ro[3*e+0], ro[3*e+1], ro[3*e+2], R);
        rodrigues(sd[3*e+0], sd[3*e+1], sd[3*e+2], U);
        float d0 = expf(sc[3*e+0]);
        float d1 = expf(sc[3*e+1]);
        float d2 = expf(sc[3*e+2]);

        // W = U * diag(d)
        float W[9];
#pragma unroll
        for (int i = 0; i < 3; ++i) {
            W[3*i+0] = U[3*i+0] * d0;
            W[3*i+1] = U[3*i+1] * d1;
            W[3*i+2] = U[3*i+2] * d2;
        }
        // S = W * U^T  (S[i][j] = sum_k W[i][k] * U[j][k])
        float S[9];
#pragma unroll
        for (int i = 0; i < 3; ++i)
#pragma unroll
            for (int j = 0; j < 3; ++j)
                S[3*i+j] = W[3*i+0]*U[3*j+0] + W[3*i+1]*U[3*j+1] + W[3*i+2]*U[3*j+2];
        // M = R * S
        float M[9];
#pragma unroll
        for (int i = 0; i < 3; ++i)
#pragma unroll
            for (int j = 0; j < 3; ++j)
                M[3*i+j] = R[3*i+0]*S[0+j] + R[3*i+1]*S[3+j] + R[3*i+2]*S[6+j];

        // Output rows: (M[r][0], M[r][1], M[r][2], trans[r]) -> one float4 each.
        int base = 12 * t + 3 * e;   // float4 index into out
        out[base + 0] = make_float4(M[0], M[1], M[2], tr[3*e+0]);
        out[base + 1] = make_float4(M[3], M[4], M[5], tr[3*e+1]);
        out[base + 2] = make_float4(M[6], M[7], M[8], tr[3*e+2]);
    }
}

extern "C" void kernel_launch(void* const* d_in, const int* in_sizes, int n_in,
                              void* d_out, int out_size, void* d_ws, size_t ws_size,
                              hipStream_t stream) {
    const float4* tr = (const float4*)d_in[0];
    const float4* ro = (const float4*)d_in[1];
    const float4* sd = (const float4*)d_in[2];
    const float4* sc = (const float4*)d_in[3];
    float4* out = (float4*)d_out;

    int Btot = in_sizes[0] / 3;     // elements (B = 2,000,000)
    int nq   = Btot / 4;            // 4 elements per thread (B % 4 == 0)
    const int threads = 256;
    int blocks = (nq + threads - 1) / threads;
    aff_kernel<<<blocks, threads, 0, stream>>>(tr, ro, sd, sc, out, nq);
}

// Round 2
// 176.165 us; speedup vs baseline: 1.2220x; 1.2220x over previous
//
#include <hip/hip_runtime.h>
#include <math.h>

#define TPB 256

// R = I + a*K + b*K^2 with K=skew(v), K^2 = v v^T - th^2 I
// => R = (1 - b*th^2) I + b * v v^T + a * K   (matches reference incl. small-angle branch)
__device__ __forceinline__ void rodrigues(float v0, float v1, float v2, float R[9]) {
    float th2 = v0 * v0 + v1 * v1 + v2 * v2;
    float th  = sqrtf(th2);
    float s, c;
    sincosf(th, &s, &c);
    bool  sm = th < 1e-6f;
    float a  = sm ? 1.0f : s / th;
    float b  = sm ? 0.5f : (1.0f - c) / th2;
    float cc = 1.0f - b * th2;
    R[0] = cc + b * v0 * v0;      R[1] = b * v0 * v1 - a * v2;  R[2] = b * v0 * v2 + a * v1;
    R[3] = b * v0 * v1 + a * v2;  R[4] = cc + b * v1 * v1;      R[5] = b * v1 * v2 - a * v0;
    R[6] = b * v0 * v2 - a * v1;  R[7] = b * v1 * v2 + a * v0;  R[8] = cc + b * v2 * v2;
}

__global__ __launch_bounds__(TPB) void aff_kernel(
    const float4* __restrict__ trans,
    const float4* __restrict__ rotat,
    const float4* __restrict__ sdir,
    const float4* __restrict__ scal,
    float4* __restrict__ out,
    int B)
{
    __shared__ float s_in[4][TPB * 3];   // 12 KB: 768 floats per input
    __shared__ float s_out[TPB * 12];    // 12 KB: flat output slab (== global layout)

    const int tid  = threadIdx.x;
    const int base = blockIdx.x * TPB;           // first element of this block
    const int n    = min(TPB, B - base);         // elements in this block (256 or tail)
    const int nf4  = (n * 3) >> 2;               // float4s per input (n*3 divisible by 4)

    // ---- coalesced global -> LDS: 192 consecutive float4 per input ----
    if (tid < nf4) {
        const int gbase = (base * 3) >> 2;       // = blockIdx.x * 192
        float4 a = trans[gbase + tid];
        float4 b = rotat[gbase + tid];
        float4 c = sdir [gbase + tid];
        float4 d = scal [gbase + tid];
        ((float4*)&s_in[0][0])[tid] = a;
        ((float4*)&s_in[1][0])[tid] = b;
        ((float4*)&s_in[2][0])[tid] = c;
        ((float4*)&s_in[3][0])[tid] = d;
    }
    __syncthreads();

    // ---- compute: one element per thread; LDS reads at stride 3 (conflict-free) ----
    if (tid < n) {
        float t0 = s_in[0][3*tid+0], t1 = s_in[0][3*tid+1], t2 = s_in[0][3*tid+2];

        float R[9], U[9];
        rodrigues(s_in[1][3*tid+0], s_in[1][3*tid+1], s_in[1][3*tid+2], R);
        rodrigues(s_in[2][3*tid+0], s_in[2][3*tid+1], s_in[2][3*tid+2], U);
        float d0 = expf(s_in[3][3*tid+0]);
        float d1 = expf(s_in[3][3*tid+1]);
        float d2 = expf(s_in[3][3*tid+2]);

        // W = U * diag(d)
        float W[9];
#pragma unroll
        for (int i = 0; i < 3; ++i) {
            W[3*i+0] = U[3*i+0] * d0;
            W[3*i+1] = U[3*i+1] * d1;
            W[3*i+2] = U[3*i+2] * d2;
        }
        // S = W * U^T
        float S[9];
#pragma unroll
        for (int i = 0; i < 3; ++i)
#pragma unroll
            for (int j = 0; j < 3; ++j)
                S[3*i+j] = W[3*i+0]*U[3*j+0] + W[3*i+1]*U[3*j+1] + W[3*i+2]*U[3*j+2];
        // M = R * S
        float M[9];
#pragma unroll
        for (int i = 0; i < 3; ++i)
#pragma unroll
            for (int j = 0; j < 3; ++j)
                M[3*i+j] = R[3*i+0]*S[0+j] + R[3*i+1]*S[3+j] + R[3*i+2]*S[6+j];

        // 12 floats -> 3 aligned float4 LDS writes (byte addr 48*tid + 16c)
        float4* so = (float4*)s_out;
        so[3*tid+0] = make_float4(M[0], M[1], M[2], t0);
        so[3*tid+1] = make_float4(M[3], M[4], M[5], t1);
        so[3*tid+2] = make_float4(M[6], M[7], M[8], t2);
    }
    __syncthreads();

    // ---- coalesced LDS -> global: 768 consecutive float4 per block ----
    const int nq = n * 3;                        // output float4 count for this block
    const float4* so = (const float4*)s_out;
    const int ob = base * 3;                     // output float4 base
#pragma unroll
    for (int p = 0; p < 3; ++p) {
        int idx = p * TPB + tid;
        if (idx < nq) out[ob + idx] = so[idx];
    }
}

extern "C" void kernel_launch(void* const* d_in, const int* in_sizes, int n_in,
                              void* d_out, int out_size, void* d_ws, size_t ws_size,
                              hipStream_t stream) {
    const float4* tr = (const float4*)d_in[0];
    const float4* ro = (const float4*)d_in[1];
    const float4* sd = (const float4*)d_in[2];
    const float4* sc = (const float4*)d_in[3];
    float4* out = (float4*)d_out;

    int B = in_sizes[0] / 3;                     // 2,000,000 elements
    int blocks = (B + TPB - 1) / TPB;
    aff_kernel<<<blocks, TPB, 0, stream>>>(tr, ro, sd, sc, out, B);
}